// Round 1
// baseline (1262.822 us; speedup 1.0000x reference)
//
#include <hip/hip_runtime.h>
#include <hip/hip_bf16.h>

#define NN 50000
#define NE 800000
#define D 128
#define NL 5
#define NR 2048
#define NO 65

// ---------------- init: h0 = keys_emb[x0] + vals_emb[x1] ----------------
__global__ void k_init(const int* __restrict__ x, const float* __restrict__ ke,
                       const float* __restrict__ ve, float* __restrict__ h) {
    int i = blockIdx.x * blockDim.x + threadIdx.x;
    if (i >= NN * D) return;
    int node = i >> 7, f = i & 127;
    int k0 = x[node * 2 + 0], v0 = x[node * 2 + 1];
    h[i] = ke[k0 * D + f] + ve[v0 * D + f];
}

// ---------------- CSR build (counting sort by dst) ----------------
__global__ void k_hist(const int* __restrict__ ei, int* __restrict__ deg) {
    int e = blockIdx.x * blockDim.x + threadIdx.x;
    if (e >= NE) return;
    atomicAdd(&deg[ei[NE + e]], 1);
}

__global__ void k_scan1(const int* __restrict__ deg, int* __restrict__ incl,
                        int* __restrict__ bsums) {
    __shared__ int s[256];
    int t = threadIdx.x, i = blockIdx.x * 256 + t;
    int v = (i < NN) ? deg[i] : 0;
    s[t] = v; __syncthreads();
    for (int off = 1; off < 256; off <<= 1) {
        int u = (t >= off) ? s[t - off] : 0;
        __syncthreads();
        s[t] += u; __syncthreads();
    }
    if (i < NN) incl[i] = s[t];
    if (t == 255) bsums[blockIdx.x] = s[255];
}

__global__ void k_scan2(int* __restrict__ bsums, int nb) {
    __shared__ int s[256];
    int t = threadIdx.x;
    int v = (t < nb) ? bsums[t] : 0;
    s[t] = v; __syncthreads();
    for (int off = 1; off < 256; off <<= 1) {
        int u = (t >= off) ? s[t - off] : 0;
        __syncthreads();
        s[t] += u; __syncthreads();
    }
    if (t < nb) bsums[t] = s[t] - v;   // exclusive
}

__global__ void k_scan3(const int* __restrict__ deg, const int* __restrict__ incl,
                        const int* __restrict__ bsums, int* __restrict__ rs,
                        int* __restrict__ cur) {
    int i = blockIdx.x * blockDim.x + threadIdx.x;
    if (i >= NN) return;
    int ex = incl[i] - deg[i] + bsums[i >> 8];
    rs[i] = ex; cur[i] = ex;
    if (i == 0) rs[NN] = NE;
}

__global__ void k_fill(const int* __restrict__ ei, int* __restrict__ cur,
                       int* __restrict__ csrc) {
    int e = blockIdx.x * blockDim.x + threadIdx.x;
    if (e >= NE) return;
    int s = ei[e], d = ei[NE + e];
    int pos = atomicAdd(&cur[d], 1);
    csrc[pos] = s;
}

// ---------------- aggregate: z = (1+eps)*h + sum_{in-edges} h[src] ----------------
// one wave (64 lanes) per node; each lane owns a float2 of the 128-dim row
__global__ void __launch_bounds__(256) k_agg(const float* __restrict__ h,
                                             const int* __restrict__ rs,
                                             const int* __restrict__ csrc,
                                             const float* __restrict__ epsArr, int layer,
                                             float* __restrict__ z) {
    int wv = (blockIdx.x * blockDim.x + threadIdx.x) >> 6;
    int lane = threadIdx.x & 63;
    if (wv >= NN) return;
    const float2* h2 = (const float2*)h;
    int e0 = rs[wv], e1 = rs[wv + 1];
    float ax = 0.f, ay = 0.f;
    for (int e = e0; e < e1; ++e) {
        int s = csrc[e];
        float2 v = h2[s * 64 + lane];
        ax += v.x; ay += v.y;
    }
    float epsl = 1.0f + epsArr[layer];
    float2 own = h2[wv * 64 + lane];
    float2 o; o.x = ax + epsl * own.x; o.y = ay + epsl * own.y;
    ((float2*)z)[wv * 64 + lane] = o;
}

// ---------------- fused MLP + residual + LayerNorm ----------------
// block = 256 threads, 32 rows. t = relu(z@W1+b1) kept in LDS; out = t@W2+b2+h, LN -> h
__global__ void __launch_bounds__(256) k_mlp(const float* __restrict__ z,
                                             float* __restrict__ h,
                                             const float* __restrict__ W1,
                                             const float* __restrict__ b1,
                                             const float* __restrict__ W2,
                                             const float* __restrict__ b2,
                                             const float* __restrict__ g,
                                             const float* __restrict__ bt, int layer) {
    __shared__ float zs[32 * 128];   // 16 KB (reused for z2 before LN)
    __shared__ float ts[32 * 256];   // 32 KB
    const int t = threadIdx.x;
    const int row0 = blockIdx.x * 32;

    // stage z rows
    for (int i = t; i < 32 * 128; i += 256) {
        int gi = row0 * 128 + i;
        zs[i] = (gi < NN * 128) ? z[gi] : 0.f;
    }
    __syncthreads();

    // ---- phase 1: t = relu(z @ W1 + b1), thread = 8 rows x 4 cols ----
    {
        const int cg = t & 63;          // 64 col-groups of 4
        const int rg = t >> 6;          // 4 row-groups of 8
        const int c0 = cg * 4;
        const float* W1p = W1 + (size_t)layer * 128 * 256;
        float acc[8][4];
        #pragma unroll
        for (int j = 0; j < 8; ++j)
            #pragma unroll
            for (int q = 0; q < 4; ++q) acc[j][q] = 0.f;

        for (int k = 0; k < 128; k += 2) {
            float4 wa = *(const float4*)&W1p[k * 256 + c0];
            float4 wb = *(const float4*)&W1p[(k + 1) * 256 + c0];
            #pragma unroll
            for (int j = 0; j < 8; ++j) {
                float2 zz = *(const float2*)&zs[(rg * 8 + j) * 128 + k];
                acc[j][0] += zz.x * wa.x + zz.y * wb.x;
                acc[j][1] += zz.x * wa.y + zz.y * wb.y;
                acc[j][2] += zz.x * wa.z + zz.y * wb.z;
                acc[j][3] += zz.x * wa.w + zz.y * wb.w;
            }
        }
        float4 bb = *(const float4*)&b1[layer * 256 + c0];
        #pragma unroll
        for (int j = 0; j < 8; ++j) {
            float4 r;
            r.x = fmaxf(acc[j][0] + bb.x, 0.f);
            r.y = fmaxf(acc[j][1] + bb.y, 0.f);
            r.z = fmaxf(acc[j][2] + bb.z, 0.f);
            r.w = fmaxf(acc[j][3] + bb.w, 0.f);
            *(float4*)&ts[(rg * 8 + j) * 256 + c0] = r;
        }
    }
    __syncthreads();

    // ---- phase 2: z2 = t @ W2 + b2 + h (residual), thread = 8 rows x 2 cols ----
    {
        const int cg = t & 63;
        const int rg = t >> 6;
        const int c0 = cg * 2;
        const float* W2p = W2 + (size_t)layer * 256 * 128;
        float acc[8][2];
        #pragma unroll
        for (int j = 0; j < 8; ++j) { acc[j][0] = 0.f; acc[j][1] = 0.f; }

        for (int k = 0; k < 256; k += 2) {
            float2 wa = *(const float2*)&W2p[k * 128 + c0];
            float2 wb = *(const float2*)&W2p[(k + 1) * 128 + c0];
            #pragma unroll
            for (int j = 0; j < 8; ++j) {
                float2 tv = *(const float2*)&ts[(rg * 8 + j) * 256 + k];
                acc[j][0] += tv.x * wa.x + tv.y * wb.x;
                acc[j][1] += tv.x * wa.y + tv.y * wb.y;
            }
        }
        float2 bb = *(const float2*)&b2[layer * 128 + c0];
        #pragma unroll
        for (int j = 0; j < 8; ++j) {
            int r = rg * 8 + j;
            int grow = row0 + r;
            float hx = 0.f, hy = 0.f;
            if (grow < NN) {
                float2 hv = *(const float2*)&h[grow * 128 + c0];
                hx = hv.x; hy = hv.y;
            }
            zs[r * 128 + c0 + 0] = acc[j][0] + bb.x + hx;
            zs[r * 128 + c0 + 1] = acc[j][1] + bb.y + hy;
        }
    }
    __syncthreads();

    // ---- LayerNorm: 8 threads per row, 16 elems each ----
    {
        int r = t >> 3, sub = t & 7;
        int grow = row0 + r;
        float s = 0.f, ss = 0.f;
        #pragma unroll
        for (int i = 0; i < 16; ++i) {
            float v = zs[r * 128 + sub * 16 + i];
            s += v; ss += v * v;
        }
        #pragma unroll
        for (int m = 1; m < 8; m <<= 1) {
            s  += __shfl_xor(s, m);
            ss += __shfl_xor(ss, m);
        }
        float mu = s * (1.f / 128.f);
        float var = ss * (1.f / 128.f) - mu * mu;
        float rstd = rsqrtf(var + 1e-5f);
        if (grow < NN) {
            #pragma unroll
            for (int i = 0; i < 16; ++i) {
                int c = sub * 16 + i;
                float v = (zs[r * 128 + c] - mu) * rstd;
                h[grow * 128 + c] = v * g[layer * 128 + c] + bt[layer * 128 + c];
            }
        }
    }
}

// ---------------- readout: out = h[roots] @ W_out ----------------
__global__ void __launch_bounds__(256) k_out(const float* __restrict__ h,
                                             const int* __restrict__ roots,
                                             const float* __restrict__ Wo,
                                             float* __restrict__ out) {
    __shared__ float hs[16 * 128];
    int t = threadIdx.x;
    int r0 = blockIdx.x * 16;
    for (int i = t; i < 16 * 128; i += 256) {
        int rr = r0 + (i >> 7);
        hs[i] = h[roots[rr] * 128 + (i & 127)];
    }
    __syncthreads();
    for (int o = t; o < 16 * NO; o += 256) {
        int j = o / NO, c = o % NO;
        float s = 0.f;
        for (int k = 0; k < 128; ++k) s += hs[j * 128 + k] * Wo[k * NO + c];
        out[(r0 + j) * NO + c] = s;
    }
}

extern "C" void kernel_launch(void* const* d_in, const int* in_sizes, int n_in,
                              void* d_out, int out_size, void* d_ws, size_t ws_size,
                              hipStream_t stream) {
    const int*   x    = (const int*)d_in[0];
    const int*   ei   = (const int*)d_in[1];
    const int*   roots= (const int*)d_in[2];
    const float* ke   = (const float*)d_in[3];
    const float* ve   = (const float*)d_in[4];
    const float* eps  = (const float*)d_in[5];
    const float* W1   = (const float*)d_in[6];
    const float* b1   = (const float*)d_in[7];
    const float* W2   = (const float*)d_in[8];
    const float* b2   = (const float*)d_in[9];
    const float* g    = (const float*)d_in[10];
    const float* bt   = (const float*)d_in[11];
    const float* Wo   = (const float*)d_in[12];
    float* out = (float*)d_out;

    char* ws = (char*)d_ws;
    size_t off = 0;
    auto alloc = [&](size_t bytes) {
        void* p = ws + off;
        off += (bytes + 255) & ~(size_t)255;
        return p;
    };
    float* h    = (float*)alloc((size_t)NN * D * 4);
    float* z    = (float*)alloc((size_t)NN * D * 4);
    int*   deg  = (int*)alloc((size_t)NN * 4);
    int*   incl = (int*)alloc((size_t)NN * 4);
    int*   bsum = (int*)alloc(256 * 4);
    int*   rs   = (int*)alloc((size_t)(NN + 1) * 4);
    int*   cur  = (int*)alloc((size_t)NN * 4);
    int*   csrc = (int*)alloc((size_t)NE * 4);

    hipMemsetAsync(deg, 0, (size_t)NN * 4, stream);

    k_init<<<(NN * D + 255) / 256, 256, 0, stream>>>(x, ke, ve, h);
    k_hist<<<(NE + 255) / 256, 256, 0, stream>>>(ei, deg);
    int nb = (NN + 255) / 256;
    k_scan1<<<nb, 256, 0, stream>>>(deg, incl, bsum);
    k_scan2<<<1, 256, 0, stream>>>(bsum, nb);
    k_scan3<<<nb, 256, 0, stream>>>(deg, incl, bsum, rs, cur);
    k_fill<<<(NE + 255) / 256, 256, 0, stream>>>(ei, cur, csrc);

    for (int l = 0; l < NL; ++l) {
        k_agg<<<(NN * 64) / 256, 256, 0, stream>>>(h, rs, csrc, eps, l, z);
        k_mlp<<<(NN + 31) / 32, 256, 0, stream>>>(z, h, W1, b1, W2, b2, g, bt, l);
    }
    k_out<<<NR / 16, 256, 0, stream>>>(h, roots, Wo, out);
}

// Round 2
// 788.867 us; speedup vs baseline: 1.6008x; 1.6008x over previous
//
#include <hip/hip_runtime.h>
#include <hip/hip_bf16.h>

#define NN 50000
#define NE 800000
#define D 128
#define NL 5
#define NR 2048
#define NO 65
#define BR 64                 // rows per MLP block
#define NBLK ((NN + BR - 1) / BR)

typedef unsigned short ushort_t;
typedef __attribute__((ext_vector_type(8))) short bf16x8;
typedef __attribute__((ext_vector_type(4))) float f32x4;

__device__ inline float bf2f(ushort_t u) {
    unsigned v = ((unsigned)u) << 16;
    return __builtin_bit_cast(float, v);
}
__device__ inline ushort_t f2bf(float f) {
    unsigned u = __builtin_bit_cast(unsigned, f);
    u = (u + 0x7FFF + ((u >> 16) & 1)) >> 16;   // RNE
    return (ushort_t)u;
}

// ---------------- init: h0 = keys_emb[x0] + vals_emb[x1] (f32 + bf16 copies) ---------
__global__ void k_init(const int* __restrict__ x, const float* __restrict__ ke,
                       const float* __restrict__ ve, float* __restrict__ h32,
                       ushort_t* __restrict__ h16) {
    int i = blockIdx.x * blockDim.x + threadIdx.x;
    if (i >= NN * D) return;
    int node = i >> 7, f = i & 127;
    float v = ke[x[node * 2 + 0] * D + f] + ve[x[node * 2 + 1] * D + f];
    h32[i] = v;
    h16[i] = f2bf(v);
}

// ---------------- weight convert+transpose to bf16 ----------------
// W1t[l][n(256)][k(128)] <- W1[l][k][n]
__global__ void k_w1t(const float* __restrict__ W1, ushort_t* __restrict__ W1t) {
    int i = blockIdx.x * blockDim.x + threadIdx.x;
    if (i >= NL * 256 * 128) return;
    int l = i / 32768, r = i % 32768;
    int n = r >> 7, k = r & 127;
    W1t[i] = f2bf(W1[l * 32768 + k * 256 + n]);
}
// W2t[l][n(128)][k(256)] <- W2[l][k][n]
__global__ void k_w2t(const float* __restrict__ W2, ushort_t* __restrict__ W2t) {
    int i = blockIdx.x * blockDim.x + threadIdx.x;
    if (i >= NL * 128 * 256) return;
    int l = i / 32768, r = i % 32768;
    int n = r >> 8, k = r & 255;
    W2t[i] = f2bf(W2[l * 32768 + k * 128 + n]);
}

// ---------------- CSR build (counting sort by dst) ----------------
__global__ void k_hist(const int* __restrict__ ei, int* __restrict__ deg) {
    int e = blockIdx.x * blockDim.x + threadIdx.x;
    if (e >= NE) return;
    atomicAdd(&deg[ei[NE + e]], 1);
}

__global__ void k_scan1(const int* __restrict__ deg, int* __restrict__ incl,
                        int* __restrict__ bsums) {
    __shared__ int s[256];
    int t = threadIdx.x, i = blockIdx.x * 256 + t;
    int v = (i < NN) ? deg[i] : 0;
    s[t] = v; __syncthreads();
    for (int off = 1; off < 256; off <<= 1) {
        int u = (t >= off) ? s[t - off] : 0;
        __syncthreads();
        s[t] += u; __syncthreads();
    }
    if (i < NN) incl[i] = s[t];
    if (t == 255) bsums[blockIdx.x] = s[255];
}

__global__ void k_scan2(int* __restrict__ bsums, int nb) {
    __shared__ int s[256];
    int t = threadIdx.x;
    int v = (t < nb) ? bsums[t] : 0;
    s[t] = v; __syncthreads();
    for (int off = 1; off < 256; off <<= 1) {
        int u = (t >= off) ? s[t - off] : 0;
        __syncthreads();
        s[t] += u; __syncthreads();
    }
    if (t < nb) bsums[t] = s[t] - v;   // exclusive
}

__global__ void k_scan3(const int* __restrict__ deg, const int* __restrict__ incl,
                        const int* __restrict__ bsums, int* __restrict__ rs,
                        int* __restrict__ cur) {
    int i = blockIdx.x * blockDim.x + threadIdx.x;
    if (i >= NN) return;
    int ex = incl[i] - deg[i] + bsums[i >> 8];
    rs[i] = ex; cur[i] = ex;
    if (i == 0) rs[NN] = NE;
}

__global__ void k_fill(const int* __restrict__ ei, int* __restrict__ cur,
                       int* __restrict__ csrc) {
    int e = blockIdx.x * blockDim.x + threadIdx.x;
    if (e >= NE) return;
    int s = ei[e], d = ei[NE + e];
    int pos = atomicAdd(&cur[d], 1);
    csrc[pos] = s;
}

// ------- aggregate: z16 = bf16( (1+eps)*h + sum_in h[src] ), bf16 gather -------
__global__ void __launch_bounds__(256) k_agg(const ushort_t* __restrict__ h16,
                                             const int* __restrict__ rs,
                                             const int* __restrict__ csrc,
                                             const float* __restrict__ epsArr, int layer,
                                             ushort_t* __restrict__ z16) {
    int wv = (blockIdx.x * blockDim.x + threadIdx.x) >> 6;
    int lane = threadIdx.x & 63;
    if (wv >= NN) return;
    const unsigned* h2 = (const unsigned*)h16;   // 2 bf16 per lane
    int e0 = rs[wv], e1 = rs[wv + 1];
    float ax = 0.f, ay = 0.f;
    for (int e = e0; e < e1; ++e) {
        unsigned p = h2[(size_t)csrc[e] * 64 + lane];
        ax += bf2f((ushort_t)(p & 0xFFFF));
        ay += bf2f((ushort_t)(p >> 16));
    }
    float epsl = 1.0f + epsArr[layer];
    unsigned own = h2[(size_t)wv * 64 + lane];
    float ox = ax + epsl * bf2f((ushort_t)(own & 0xFFFF));
    float oy = ay + epsl * bf2f((ushort_t)(own >> 16));
    ((unsigned*)z16)[(size_t)wv * 64 + lane] =
        (unsigned)f2bf(ox) | ((unsigned)f2bf(oy) << 16);
}

// ---------------- fused MFMA MLP + residual + LayerNorm ----------------
// 64 rows/block, 256 threads (4 waves). z16 -> [relu(z@W1+b1)] -> @W2+b2 + h -> LN -> h
__global__ void __launch_bounds__(256) k_mlp(const ushort_t* __restrict__ z16,
                                             float* __restrict__ h32,
                                             ushort_t* __restrict__ h16,
                                             const ushort_t* __restrict__ W1t,
                                             const float* __restrict__ b1,
                                             const ushort_t* __restrict__ W2t,
                                             const float* __restrict__ b2,
                                             const float* __restrict__ g,
                                             const float* __restrict__ bt, int layer) {
    __shared__ ushort_t zs[64 * 128];   // 16 KB, XOR-swizzled rows (256 B/row)
    __shared__ ushort_t ts[64 * 256];   // 32 KB, XOR-swizzled rows (512 B/row)
    const int t = threadIdx.x;
    const int lane = t & 63, w = t >> 6;
    const int lr = lane & 15, lk = lane >> 4;       // MFMA row/col & k-group
    const int row0 = blockIdx.x * BR;

    // ---- stage z tile into swizzled LDS (16 B per thread per iter) ----
    #pragma unroll
    for (int it = 0; it < 4; ++it) {
        int idx = it * 256 + t;         // 1024 units of 16 B
        int row = idx >> 4;             // 16 units per 128-bf16 row
        int colu = idx & 15;
        uint4 v = {0u, 0u, 0u, 0u};
        if (row0 + row < NN)
            v = *(const uint4*)(z16 + (size_t)(row0 + row) * 128 + colu * 8);
        int byte = (row * 256 + colu * 16) ^ ((row & 7) << 4);
        *(uint4*)((char*)zs + byte) = v;
    }
    __syncthreads();

    // ---- phase 1: C1(64x256) = z @ W1t^T; wave w owns col-tiles 4w..4w+3 ----
    const ushort_t* W1p = W1t + (size_t)layer * 256 * 128;
    f32x4 acc[4][4] = {};               // [rt][ct]
    #pragma unroll
    for (int kk = 0; kk < 4; ++kk) {    // K = 128 = 4 x 32
        bf16x8 a[4];
        #pragma unroll
        for (int rt = 0; rt < 4; ++rt) {
            int row = rt * 16 + lr;
            int byte = (row * 256 + kk * 64 + lk * 16) ^ ((row & 7) << 4);
            a[rt] = *(const bf16x8*)((const char*)zs + byte);
        }
        #pragma unroll
        for (int ct = 0; ct < 4; ++ct) {
            int col = (w * 4 + ct) * 16 + lr;
            bf16x8 b = *(const bf16x8*)(W1p + (size_t)col * 128 + kk * 32 + lk * 8);
            #pragma unroll
            for (int rt = 0; rt < 4; ++rt)
                acc[rt][ct] = __builtin_amdgcn_mfma_f32_16x16x32_bf16(
                    a[rt], b, acc[rt][ct], 0, 0, 0);
        }
    }
    // relu + bias -> bf16 ts (swizzled)
    #pragma unroll
    for (int ct = 0; ct < 4; ++ct) {
        int col = (w * 4 + ct) * 16 + lr;
        float bb = b1[layer * 256 + col];
        #pragma unroll
        for (int rt = 0; rt < 4; ++rt)
            #pragma unroll
            for (int r = 0; r < 4; ++r) {
                int row = rt * 16 + lk * 4 + r;
                float v = fmaxf(acc[rt][ct][r] + bb, 0.f);
                int byte = (row * 512 + col * 2) ^ ((row & 7) << 4);
                *(ushort_t*)((char*)ts + byte) = f2bf(v);
            }
    }
    __syncthreads();

    // ---- phase 2: C2(64x128) = t @ W2t^T; wave w owns row-tile w, all 8 col-tiles ----
    const ushort_t* W2p = W2t + (size_t)layer * 128 * 256;
    bf16x8 a2[8];
    #pragma unroll
    for (int kk = 0; kk < 8; ++kk) {    // K = 256 = 8 x 32
        int row = w * 16 + lr;
        int byte = (row * 512 + kk * 64 + lk * 16) ^ ((row & 7) << 4);
        a2[kk] = *(const bf16x8*)((const char*)ts + byte);
    }
    f32x4 acc2[8] = {};
    #pragma unroll
    for (int ct = 0; ct < 8; ++ct) {
        int col = ct * 16 + lr;
        #pragma unroll
        for (int kk = 0; kk < 8; ++kk) {
            bf16x8 b = *(const bf16x8*)(W2p + (size_t)col * 256 + kk * 32 + lk * 8);
            acc2[ct] = __builtin_amdgcn_mfma_f32_16x16x32_bf16(a2[kk], b, acc2[ct], 0, 0, 0);
        }
    }

    // ---- bias + residual + in-register LayerNorm ----
    // lane holds rows (w*16 + lk*4 + r), cols (ct*16 + lr)
    float vals[4][8];
    #pragma unroll
    for (int ct = 0; ct < 8; ++ct) {
        int col = ct * 16 + lr;
        float bb = b2[layer * 128 + col];
        #pragma unroll
        for (int r = 0; r < 4; ++r) {
            int grow = row0 + w * 16 + lk * 4 + r;
            float hv = (grow < NN) ? h32[(size_t)grow * 128 + col] : 0.f;
            vals[r][ct] = acc2[ct][r] + bb + hv;
        }
    }
    #pragma unroll
    for (int r = 0; r < 4; ++r) {
        float s = 0.f, ss = 0.f;
        #pragma unroll
        for (int ct = 0; ct < 8; ++ct) { s += vals[r][ct]; ss += vals[r][ct] * vals[r][ct]; }
        #pragma unroll
        for (int m = 1; m < 16; m <<= 1) {
            s  += __shfl_xor(s, m);
            ss += __shfl_xor(ss, m);
        }
        float mu = s * (1.f / 128.f);
        float var = ss * (1.f / 128.f) - mu * mu;
        float rstd = rsqrtf(var + 1e-5f);
        int grow = row0 + w * 16 + lk * 4 + r;
        if (grow < NN) {
            #pragma unroll
            for (int ct = 0; ct < 8; ++ct) {
                int col = ct * 16 + lr;
                float o = (vals[r][ct] - mu) * rstd * g[layer * 128 + col] + bt[layer * 128 + col];
                h32[(size_t)grow * 128 + col] = o;
                h16[(size_t)grow * 128 + col] = f2bf(o);
            }
        }
    }
}

// ---------------- readout: out = h[roots] @ W_out ----------------
__global__ void __launch_bounds__(256) k_out(const float* __restrict__ h,
                                             const int* __restrict__ roots,
                                             const float* __restrict__ Wo,
                                             float* __restrict__ out) {
    __shared__ float hs[16 * 128];
    int t = threadIdx.x;
    int r0 = blockIdx.x * 16;
    for (int i = t; i < 16 * 128; i += 256) {
        int rr = r0 + (i >> 7);
        hs[i] = h[(size_t)roots[rr] * 128 + (i & 127)];
    }
    __syncthreads();
    for (int o = t; o < 16 * NO; o += 256) {
        int j = o / NO, c = o % NO;
        float s = 0.f;
        for (int k = 0; k < 128; ++k) s += hs[j * 128 + k] * Wo[k * NO + c];
        out[(r0 + j) * NO + c] = s;
    }
}

extern "C" void kernel_launch(void* const* d_in, const int* in_sizes, int n_in,
                              void* d_out, int out_size, void* d_ws, size_t ws_size,
                              hipStream_t stream) {
    const int*   x    = (const int*)d_in[0];
    const int*   ei   = (const int*)d_in[1];
    const int*   roots= (const int*)d_in[2];
    const float* ke   = (const float*)d_in[3];
    const float* ve   = (const float*)d_in[4];
    const float* eps  = (const float*)d_in[5];
    const float* W1   = (const float*)d_in[6];
    const float* b1   = (const float*)d_in[7];
    const float* W2   = (const float*)d_in[8];
    const float* b2   = (const float*)d_in[9];
    const float* g    = (const float*)d_in[10];
    const float* bt   = (const float*)d_in[11];
    const float* Wo   = (const float*)d_in[12];
    float* out = (float*)d_out;

    char* ws = (char*)d_ws;
    size_t off = 0;
    auto alloc = [&](size_t bytes) {
        void* p = ws + off;
        off += (bytes + 255) & ~(size_t)255;
        return p;
    };
    float*    h32  = (float*)alloc((size_t)NN * D * 4);
    ushort_t* h16  = (ushort_t*)alloc((size_t)NN * D * 2);
    ushort_t* z16  = (ushort_t*)alloc((size_t)NBLK * BR * D * 2);  // padded rows
    ushort_t* W1tb = (ushort_t*)alloc((size_t)NL * 256 * 128 * 2);
    ushort_t* W2tb = (ushort_t*)alloc((size_t)NL * 128 * 256 * 2);
    int* deg  = (int*)alloc((size_t)NN * 4);
    int* incl = (int*)alloc((size_t)NN * 4);
    int* bsum = (int*)alloc(256 * 4);
    int* rs   = (int*)alloc((size_t)(NN + 1) * 4);
    int* cur  = (int*)alloc((size_t)NN * 4);
    int* csrc = (int*)alloc((size_t)NE * 4);

    hipMemsetAsync(deg, 0, (size_t)NN * 4, stream);

    k_init<<<(NN * D + 255) / 256, 256, 0, stream>>>(x, ke, ve, h32, h16);
    k_w1t<<<(NL * 32768 + 255) / 256, 256, 0, stream>>>(W1, W1tb);
    k_w2t<<<(NL * 32768 + 255) / 256, 256, 0, stream>>>(W2, W2tb);
    k_hist<<<(NE + 255) / 256, 256, 0, stream>>>(ei, deg);
    int nb = (NN + 255) / 256;
    k_scan1<<<nb, 256, 0, stream>>>(deg, incl, bsum);
    k_scan2<<<1, 256, 0, stream>>>(bsum, nb);
    k_scan3<<<nb, 256, 0, stream>>>(deg, incl, bsum, rs, cur);
    k_fill<<<(NE + 255) / 256, 256, 0, stream>>>(ei, cur, csrc);

    for (int l = 0; l < NL; ++l) {
        k_agg<<<(NN * 64 + 255) / 256, 256, 0, stream>>>(h16, rs, csrc, eps, l, z16);
        k_mlp<<<NBLK, 256, 0, stream>>>(z16, h32, h16, W1tb, b1, W2tb, b2, g, bt, l);
    }
    k_out<<<NR / 16, 256, 0, stream>>>(h32, roots, Wo, out);
}